// Round 1
// baseline (395.550 us; speedup 1.0000x reference)
//
#include <hip/hip_runtime.h>
#include <math.h>

// Problem constants
static constexpr int GRIDN = 30;
static constexpr int S    = 900;     // GRIDN*GRIDN
static constexpr int D    = 512;
static constexpr int HQ   = 8;
static constexpr int HKV  = 2;
static constexpr int DH   = 64;
static constexpr int T    = 16;
static constexpr int NTOK = 1 + T*S + S;   // 15301
static constexpr int CUR0 = 1 + T*S;       // 14401
static constexpr int NKEY = S + 1 + T;     // 917 valid keys per query

// ---------------------------------------------------------------------------
// KV projection GEMM with token gather.
// Computes K[l][0:128] = tokens[l] @ Wk^T, V likewise. Tiles: 64 rows x 64 cols.
// grid = (ceil(NTOK/64)=240, 4): by 0..1 -> Wk cols 0..127, by 2..3 -> Wv.
// ---------------------------------------------------------------------------
__global__ __launch_bounds__(256) void gemm_kv(
    const float* __restrict__ init_e, const float* __restrict__ hist,
    const float* __restrict__ cur, const float* __restrict__ Wk,
    const float* __restrict__ Wv, float* __restrict__ Kw, float* __restrict__ Vw)
{
    __shared__ __align__(16) float As[16][68];
    __shared__ __align__(16) float Bs[16][68];
    const int l0 = blockIdx.x * 64;
    const int by = blockIdx.y;
    const float* W = (by < 2) ? Wk : Wv;
    float* O       = (by < 2) ? Kw : Vw;
    const int cb = (by & 1) * 64;

    const int tid = threadIdx.x;
    const int lr  = tid >> 2;          // 0..63 (row for A, col-row for B loads)
    const int dk4 = (tid & 3) << 2;    // 0,4,8,12
    const int ty  = tid >> 4;          // 0..15
    const int tx  = tid & 15;          // 0..15

    float acc[4][4] = {};

    for (int k0 = 0; k0 < 512; k0 += 16) {
        // --- load A tile (64 tokens x 16 dims), transposed into LDS ---
        float4 a4 = make_float4(0.f, 0.f, 0.f, 0.f);
        const int l = l0 + lr;
        if (l < NTOK) {
            const float* row = (l == 0) ? init_e
                             : (l <= T*S ? hist + (size_t)(l - 1) * 512
                                         : cur  + (size_t)(l - CUR0) * 512);
            a4 = *(const float4*)(row + k0 + dk4);
        }
        As[dk4+0][lr] = a4.x; As[dk4+1][lr] = a4.y;
        As[dk4+2][lr] = a4.z; As[dk4+3][lr] = a4.w;
        // --- load B tile (64 W-rows x 16 dims), transposed ---
        float4 b4 = *(const float4*)(W + (size_t)(cb + lr) * 512 + k0 + dk4);
        Bs[dk4+0][lr] = b4.x; Bs[dk4+1][lr] = b4.y;
        Bs[dk4+2][lr] = b4.z; Bs[dk4+3][lr] = b4.w;
        __syncthreads();
        #pragma unroll
        for (int kk = 0; kk < 16; ++kk) {
            const float4 av = *(const float4*)&As[kk][ty << 2];
            const float4 bv = *(const float4*)&Bs[kk][tx << 2];
            const float a_[4] = {av.x, av.y, av.z, av.w};
            const float b_[4] = {bv.x, bv.y, bv.z, bv.w};
            #pragma unroll
            for (int i = 0; i < 4; ++i)
                #pragma unroll
                for (int j = 0; j < 4; ++j)
                    acc[i][j] = fmaf(a_[i], b_[j], acc[i][j]);
        }
        __syncthreads();
    }
    #pragma unroll
    for (int i = 0; i < 4; ++i) {
        const int l = l0 + (ty << 2) + i;
        if (l >= NTOK) continue;
        float4 o4 = make_float4(acc[i][0], acc[i][1], acc[i][2], acc[i][3]);
        *(float4*)(O + (size_t)l * 128 + cb + (tx << 2)) = o4;
    }
}

// ---------------------------------------------------------------------------
// Generic Out[M][N] = A[M][512] @ W[N][512]^T   (N multiple of 64)
// ---------------------------------------------------------------------------
__global__ __launch_bounds__(256) void gemm_wt(
    const float* __restrict__ A, const float* __restrict__ W,
    float* __restrict__ Out, int M, int N)
{
    __shared__ __align__(16) float As[16][68];
    __shared__ __align__(16) float Bs[16][68];
    const int l0 = blockIdx.x * 64;
    const int n0 = blockIdx.y * 64;
    const int tid = threadIdx.x;
    const int lr  = tid >> 2;
    const int dk4 = (tid & 3) << 2;
    const int ty  = tid >> 4;
    const int tx  = tid & 15;

    float acc[4][4] = {};

    for (int k0 = 0; k0 < 512; k0 += 16) {
        float4 a4 = make_float4(0.f, 0.f, 0.f, 0.f);
        const int l = l0 + lr;
        if (l < M) a4 = *(const float4*)(A + (size_t)l * 512 + k0 + dk4);
        As[dk4+0][lr] = a4.x; As[dk4+1][lr] = a4.y;
        As[dk4+2][lr] = a4.z; As[dk4+3][lr] = a4.w;
        float4 b4 = *(const float4*)(W + (size_t)(n0 + lr) * 512 + k0 + dk4);
        Bs[dk4+0][lr] = b4.x; Bs[dk4+1][lr] = b4.y;
        Bs[dk4+2][lr] = b4.z; Bs[dk4+3][lr] = b4.w;
        __syncthreads();
        #pragma unroll
        for (int kk = 0; kk < 16; ++kk) {
            const float4 av = *(const float4*)&As[kk][ty << 2];
            const float4 bv = *(const float4*)&Bs[kk][tx << 2];
            const float a_[4] = {av.x, av.y, av.z, av.w};
            const float b_[4] = {bv.x, bv.y, bv.z, bv.w};
            #pragma unroll
            for (int i = 0; i < 4; ++i)
                #pragma unroll
                for (int j = 0; j < 4; ++j)
                    acc[i][j] = fmaf(a_[i], b_[j], acc[i][j]);
        }
        __syncthreads();
    }
    #pragma unroll
    for (int i = 0; i < 4; ++i) {
        const int l = l0 + (ty << 2) + i;
        if (l >= M) continue;
        float4 o4 = make_float4(acc[i][0], acc[i][1], acc[i][2], acc[i][3]);
        *(float4*)(Out + (size_t)l * N + n0 + (tx << 2)) = o4;
    }
}

// ---------------------------------------------------------------------------
// RoPE in place on Q [900][8][64] and K [15301][2][64].
// Composite rotation per adjacent pair j: theta = pos*inv1d[j] + c*inv2d[j&15],
// c = gy for j<16, gx for j>=16.
// ---------------------------------------------------------------------------
__global__ void rope_kernel(float* __restrict__ Qw, float* __restrict__ Kw)
{
    const int NQP = S * HQ * 32;       // 230400
    const int NKP = NTOK * HKV * 32;   // 979264
    const int idx = blockIdx.x * blockDim.x + threadIdx.x;
    if (idx >= NQP + NKP) return;

    float pos, cy, cx;
    float* p;
    int j;
    if (idx < NQP) {
        const int s   = idx >> 8;        // / (8*32)
        const int rem = idx & 255;
        const int h   = rem >> 5;
        j = rem & 31;
        pos = (float)T;
        cy = (float)(s / GRIDN);
        cx = (float)(s % GRIDN);
        p = Qw + (size_t)s * 512 + h * 64 + 2 * j;
    } else {
        const int k   = idx - NQP;
        const int l   = k >> 6;          // / (2*32)
        const int rem = k & 63;
        const int kvh = rem >> 5;
        j = rem & 31;
        int cell;
        if (l == 0)          { pos = 0.f;  cell = 0; }
        else if (l <= T*S)   { const int j2 = l - 1; pos = (float)(j2 / S); cell = j2 % S; }
        else                 { pos = (float)T; cell = l - CUR0; }
        cy = (float)(cell / GRIDN);
        cx = (float)(cell % GRIDN);
        p = Kw + (size_t)l * 128 + kvh * 64 + 2 * j;
    }
    const float LN1E4 = 9.210340371976184f;
    const float inv1 = expf(-(float)j        * (LN1E4 / 32.f));
    const float inv2 = expf(-(float)(j & 15) * (LN1E4 / 16.f));
    const float c2 = (j < 16) ? cy : cx;
    const float theta = pos * inv1 + c2 * inv2;
    float sn, cs;
    sincosf(theta, &sn, &cs);
    const float xr = p[0], xi = p[1];
    p[0] = xr * cs - xi * sn;
    p[1] = xr * sn + xi * cs;
}

// ---------------------------------------------------------------------------
// Attention: block = (16-query tile, head). Full 917-key score row in LDS.
// Key columns: [0,900) = current tokens, 900 = init, 901+t = history t (same cell).
// ---------------------------------------------------------------------------
__global__ __launch_bounds__(256) void attn_kernel(
    const float* __restrict__ Qw, const float* __restrict__ Kw,
    const float* __restrict__ Vw, float* __restrict__ Ow)
{
    __shared__ __align__(16) float sc[16][921];   // padded stride: conflict-free PV reads
    __shared__ __align__(16) float Qs[16][68];
    __shared__ float red[16][16];
    __shared__ float rowm[16];
    __shared__ float rowinv[16];

    const int q0  = blockIdx.x * 16;
    const int h   = blockIdx.y;
    const int kvh = h >> 2;
    const int tid = threadIdx.x;

    // load Q tile (zeros for OOB rows)
    {
        const int r = tid >> 4, dq = (tid & 15) << 2;
        const int s = q0 + r;
        float4 v = make_float4(0.f, 0.f, 0.f, 0.f);
        if (s < S) v = *(const float4*)(Qw + (size_t)s * 512 + h * 64 + dq);
        *(float4*)&Qs[r][dq] = v;
    }
    __syncthreads();

    const int r = tid & 15;
    const int g = tid >> 4;        // 0..15
    const int s = q0 + r;
    const int ssafe = (s < S) ? s : 0;

    // dense scores vs the 900 current keys
    for (int c = g; c < S; c += 16) {
        const float* kp = Kw + (size_t)(CUR0 + c) * 128 + kvh * 64;
        float acc = 0.f;
        #pragma unroll
        for (int d = 0; d < 64; d += 4) {
            const float4 qv = *(const float4*)&Qs[r][d];
            const float4 kv = *(const float4*)(kp + d);
            acc = fmaf(qv.x, kv.x, acc); acc = fmaf(qv.y, kv.y, acc);
            acc = fmaf(qv.z, kv.z, acc); acc = fmaf(qv.w, kv.w, acc);
        }
        sc[r][c] = acc * 0.125f;
    }
    // 17 extra keys: init token + 16 same-cell history tokens
    for (int e = g; e < 1 + T; e += 16) {
        const int l = (e == 0) ? 0 : (1 + (e - 1) * S + ssafe);
        const float* kp = Kw + (size_t)l * 128 + kvh * 64;
        float acc = 0.f;
        #pragma unroll
        for (int d = 0; d < 64; d += 4) {
            const float4 qv = *(const float4*)&Qs[r][d];
            const float4 kv = *(const float4*)(kp + d);
            acc = fmaf(qv.x, kv.x, acc); acc = fmaf(qv.y, kv.y, acc);
            acc = fmaf(qv.z, kv.z, acc); acc = fmaf(qv.w, kv.w, acc);
        }
        sc[r][S + e] = acc * 0.125f;
    }
    __syncthreads();

    // stable softmax over 917 cols per row
    float lm = -INFINITY;
    for (int c = g; c < NKEY; c += 16) lm = fmaxf(lm, sc[r][c]);
    red[r][g] = lm;
    __syncthreads();
    if (tid < 16) {
        float m = red[tid][0];
        #pragma unroll
        for (int g2 = 1; g2 < 16; ++g2) m = fmaxf(m, red[tid][g2]);
        rowm[tid] = m;
    }
    __syncthreads();
    const float m = rowm[r];
    float ls = 0.f;
    for (int c = g; c < NKEY; c += 16) {
        const float e = __expf(sc[r][c] - m);
        sc[r][c] = e;
        ls += e;
    }
    red[r][g] = ls;
    __syncthreads();
    if (tid < 16) {
        float sum = red[tid][0];
        #pragma unroll
        for (int g2 = 1; g2 < 16; ++g2) sum += red[tid][g2];
        rowinv[tid] = 1.f / sum;
    }
    __syncthreads();

    // PV: thread owns (row r, dims dg..dg+3)
    const float inv = rowinv[r];
    const int dg = g << 2;
    float ox = 0.f, oy = 0.f, oz = 0.f, ow = 0.f;
    for (int kk = 0; kk < NKEY; ++kk) {
        const float p = sc[r][kk];
        int l;
        if (kk < S)           l = CUR0 + kk;
        else if (kk == S)     l = 0;
        else                  l = 1 + (kk - S - 1) * S + ssafe;
        const float4 v = *(const float4*)(Vw + (size_t)l * 128 + kvh * 64 + dg);
        ox = fmaf(p, v.x, ox); oy = fmaf(p, v.y, oy);
        oz = fmaf(p, v.z, oz); ow = fmaf(p, v.w, ow);
    }
    if (s < S) {
        float4 o4 = make_float4(ox * inv, oy * inv, oz * inv, ow * inv);
        *(float4*)(Ow + (size_t)s * 512 + h * 64 + dg) = o4;
    }
}

// ---------------------------------------------------------------------------
extern "C" void kernel_launch(void* const* d_in, const int* in_sizes, int n_in,
                              void* d_out, int out_size, void* d_ws, size_t ws_size,
                              hipStream_t stream)
{
    (void)in_sizes; (void)n_in; (void)out_size; (void)ws_size;
    const float* static_grid = (const float*)d_in[0];
    const float* history     = (const float*)d_in[1];
    const float* init_embed  = (const float*)d_in[2];
    const float* Wq = (const float*)d_in[3];
    const float* Wk = (const float*)d_in[4];
    const float* Wv = (const float*)d_in[5];
    const float* Wo = (const float*)d_in[6];
    float* out = (float*)d_out;

    // workspace layout (floats): K | V | Q | O  == 18.5 MB total
    float* Kw = (float*)d_ws;
    float* Vw = Kw + (size_t)NTOK * 128;
    float* Qw = Vw + (size_t)NTOK * 128;
    float* Ow = Qw + (size_t)S * D;

    // 1) K,V projections for all 15301 tokens
    gemm_kv<<<dim3(240, 4), 256, 0, stream>>>(init_embed, history, static_grid,
                                              Wk, Wv, Kw, Vw);
    // 2) Q projection for the 900 current tokens
    gemm_wt<<<dim3(15, 8), 256, 0, stream>>>(static_grid, Wq, Qw, S, D);
    // 3) RoPE in place on Q and K
    {
        const int total = S * HQ * 32 + NTOK * HKV * 32;
        rope_kernel<<<(total + 255) / 256, 256, 0, stream>>>(Qw, Kw);
    }
    // 4) masked attention (917 keys per query)
    attn_kernel<<<dim3((S + 15) / 16, HQ), 256, 0, stream>>>(Qw, Kw, Vw, Ow);
    // 5) output projection
    gemm_wt<<<dim3(15, 8), 256, 0, stream>>>(Ow, Wo, out, S, D);
}

// Round 2
// 178.672 us; speedup vs baseline: 2.2138x; 2.2138x over previous
//
#include <hip/hip_runtime.h>
#include <math.h>

// Problem constants
static constexpr int GRIDN = 30;
static constexpr int S    = 900;
static constexpr int D    = 512;
static constexpr int HQ   = 8;
static constexpr int HKV  = 2;
static constexpr int T    = 16;
static constexpr int NTOK = 1 + T*S + S;   // 15301
static constexpr int CUR0 = 1 + T*S;       // 14401

static constexpr int KHROWS = 15360;       // Kh padded rows
static constexpr int VFROWS = 15424;       // V fp32 padded rows
static constexpr int VTC    = 960;         // Vt columns (keys CUR0..CUR0+959)
static constexpr int PBS    = 952;         // P LDS row stride (halves), 16B-aligned rows

typedef _Float16 half8   __attribute__((ext_vector_type(8)));
typedef float    floatx4 __attribute__((ext_vector_type(4)));

__device__ __forceinline__ half8 to_half8(float4 a, float4 b) {
    half8 h;
    h[0]=(_Float16)a.x; h[1]=(_Float16)a.y; h[2]=(_Float16)a.z; h[3]=(_Float16)a.w;
    h[4]=(_Float16)b.x; h[5]=(_Float16)b.y; h[6]=(_Float16)b.z; h[7]=(_Float16)b.w;
    return h;
}

#define MFMA16(a,b,c) __builtin_amdgcn_mfma_f32_16x16x32_f16((a),(b),(c),0,0,0)

// ---------------------------------------------------------------------------
// Convert weights fp32 -> fp16. Wq(512x512) Wk(128x512) Wv(128x512) Wo(512x512)
// Whkv rows 0..127 = Wk, 128..255 = Wv.  81920 threads x 8 elems.
// ---------------------------------------------------------------------------
__global__ __launch_bounds__(256) void convert_w(
    const float* __restrict__ Wq, const float* __restrict__ Wk,
    const float* __restrict__ Wv, const float* __restrict__ Wo,
    _Float16* __restrict__ Wqh, _Float16* __restrict__ Whkv, _Float16* __restrict__ Woh)
{
    const int t = blockIdx.x * 256 + threadIdx.x;
    const int i8 = t * 8;
    const float* src; _Float16* dst; int off;
    if (i8 < 262144)      { src = Wq; dst = Wqh;          off = i8; }
    else if (i8 < 327680) { src = Wk; dst = Whkv;         off = i8 - 262144; }
    else if (i8 < 393216) { src = Wv; dst = Whkv + 65536; off = i8 - 327680; }
    else                  { src = Wo; dst = Woh;          off = i8 - 393216; }
    const float4 f0 = *(const float4*)(src + off);
    const float4 f1 = *(const float4*)(src + off + 4);
    *(half8*)(dst + off) = to_half8(f0, f1);
}

// ---------------------------------------------------------------------------
// KV projection: tokens(gathered fp32) @ Whkv^T -> Kh fp16 [KHROWS][128],
// Vf fp32 [VFROWS][128]. Block = 32 rows x 256 cols, 4 waves (wave w: cols w*64).
// MFMA frags loaded directly from global (no LDS).
// ---------------------------------------------------------------------------
__global__ __launch_bounds__(256) void gemm_kv(
    const float* __restrict__ init_e, const float* __restrict__ hist,
    const float* __restrict__ cur, const _Float16* __restrict__ Whkv,
    _Float16* __restrict__ Kh, float* __restrict__ Vf)
{
    const int tid = threadIdx.x;
    const int w = tid >> 6, lane = tid & 63;
    const int r = lane & 15, kb = lane >> 4;
    const int l0 = blockIdx.x * 32;

    const float* rowp[2];
    #pragma unroll
    for (int mt = 0; mt < 2; ++mt) {
        int l = l0 + mt*16 + r;
        if (l >= NTOK) l = 0;
        rowp[mt] = (l == 0) ? init_e
                 : (l <= T*S ? hist + (size_t)(l-1)*512
                             : cur  + (size_t)(l-CUR0)*512);
    }
    const _Float16* bp[4];
    #pragma unroll
    for (int nt = 0; nt < 4; ++nt)
        bp[nt] = Whkv + (size_t)(w*64 + nt*16 + r) * 512 + kb*8;

    floatx4 acc[2][4] = {};
    for (int k0 = 0; k0 < 512; k0 += 32) {
        half8 a[2], b[4];
        #pragma unroll
        for (int mt = 0; mt < 2; ++mt) {
            const float4 f0 = *(const float4*)(rowp[mt] + k0 + kb*8);
            const float4 f1 = *(const float4*)(rowp[mt] + k0 + kb*8 + 4);
            a[mt] = to_half8(f0, f1);
        }
        #pragma unroll
        for (int nt = 0; nt < 4; ++nt) b[nt] = *(const half8*)(bp[nt] + k0);
        #pragma unroll
        for (int mt = 0; mt < 2; ++mt)
            #pragma unroll
            for (int nt = 0; nt < 4; ++nt)
                acc[mt][nt] = MFMA16(a[mt], b[nt], acc[mt][nt]);
    }
    #pragma unroll
    for (int mt = 0; mt < 2; ++mt)
        #pragma unroll
        for (int nt = 0; nt < 4; ++nt) {
            const int c = w*64 + nt*16 + r;   // 0..255, wave-uniform K/V split
            #pragma unroll
            for (int i = 0; i < 4; ++i) {
                const int l = l0 + mt*16 + kb*4 + i;
                if (l >= NTOK) continue;
                if (c < 128) Kh[(size_t)l*128 + c]       = (_Float16)acc[mt][nt][i];
                else         Vf[(size_t)l*128 + (c-128)] = acc[mt][nt][i];
            }
        }
}

// ---------------------------------------------------------------------------
// Out(fp16)[M][512] = A(fp32)[M][512] @ Wh^T.  grid (ceil(M/32), 2).
// ---------------------------------------------------------------------------
__global__ __launch_bounds__(256) void gemm_a32(
    const float* __restrict__ A, const _Float16* __restrict__ Wh,
    _Float16* __restrict__ Out, int M)
{
    const int tid = threadIdx.x;
    const int w = tid >> 6, lane = tid & 63;
    const int r = lane & 15, kb = lane >> 4;
    const int l0 = blockIdx.x * 32;
    const int n0 = blockIdx.y * 256 + w*64;

    const float* rowp[2];
    #pragma unroll
    for (int mt = 0; mt < 2; ++mt) {
        int l = l0 + mt*16 + r;
        if (l >= M) l = 0;              // clamp: A is exactly M rows
        rowp[mt] = A + (size_t)l*512;
    }
    const _Float16* bp[4];
    #pragma unroll
    for (int nt = 0; nt < 4; ++nt)
        bp[nt] = Wh + (size_t)(n0 + nt*16 + r) * 512 + kb*8;

    floatx4 acc[2][4] = {};
    for (int k0 = 0; k0 < 512; k0 += 32) {
        half8 a[2], b[4];
        #pragma unroll
        for (int mt = 0; mt < 2; ++mt) {
            const float4 f0 = *(const float4*)(rowp[mt] + k0 + kb*8);
            const float4 f1 = *(const float4*)(rowp[mt] + k0 + kb*8 + 4);
            a[mt] = to_half8(f0, f1);
        }
        #pragma unroll
        for (int nt = 0; nt < 4; ++nt) b[nt] = *(const half8*)(bp[nt] + k0);
        #pragma unroll
        for (int mt = 0; mt < 2; ++mt)
            #pragma unroll
            for (int nt = 0; nt < 4; ++nt)
                acc[mt][nt] = MFMA16(a[mt], b[nt], acc[mt][nt]);
    }
    #pragma unroll
    for (int mt = 0; mt < 2; ++mt)
        #pragma unroll
        for (int nt = 0; nt < 4; ++nt)
            #pragma unroll
            for (int i = 0; i < 4; ++i) {
                const int l = l0 + mt*16 + kb*4 + i;
                if (l < M)
                    Out[(size_t)l*512 + n0 + nt*16 + r] = (_Float16)acc[mt][nt][i];
            }
}

// ---------------------------------------------------------------------------
// Out(fp32)[M][512] = A(fp16, >=928 rows)[.][512] @ Wh^T.  grid (ceil(M/32), 2).
// ---------------------------------------------------------------------------
__global__ __launch_bounds__(256) void gemm_a16(
    const _Float16* __restrict__ A, const _Float16* __restrict__ Wh,
    float* __restrict__ Out, int M)
{
    const int tid = threadIdx.x;
    const int w = tid >> 6, lane = tid & 63;
    const int r = lane & 15, kb = lane >> 4;
    const int l0 = blockIdx.x * 32;
    const int n0 = blockIdx.y * 256 + w*64;

    const _Float16* ap[2];
    #pragma unroll
    for (int mt = 0; mt < 2; ++mt)
        ap[mt] = A + (size_t)(l0 + mt*16 + r)*512 + kb*8;   // rows padded to 928
    const _Float16* bp[4];
    #pragma unroll
    for (int nt = 0; nt < 4; ++nt)
        bp[nt] = Wh + (size_t)(n0 + nt*16 + r) * 512 + kb*8;

    floatx4 acc[2][4] = {};
    for (int k0 = 0; k0 < 512; k0 += 32) {
        half8 a[2], b[4];
        #pragma unroll
        for (int mt = 0; mt < 2; ++mt) a[mt] = *(const half8*)(ap[mt] + k0);
        #pragma unroll
        for (int nt = 0; nt < 4; ++nt) b[nt] = *(const half8*)(bp[nt] + k0);
        #pragma unroll
        for (int mt = 0; mt < 2; ++mt)
            #pragma unroll
            for (int nt = 0; nt < 4; ++nt)
                acc[mt][nt] = MFMA16(a[mt], b[nt], acc[mt][nt]);
    }
    #pragma unroll
    for (int mt = 0; mt < 2; ++mt)
        #pragma unroll
        for (int nt = 0; nt < 4; ++nt)
            #pragma unroll
            for (int i = 0; i < 4; ++i) {
                const int l = l0 + mt*16 + kb*4 + i;
                if (l < M)
                    Out[(size_t)l*512 + n0 + nt*16 + r] = acc[mt][nt][i];
            }
}

// ---------------------------------------------------------------------------
// RoPE in place on fp16 Qh [>=900][512] and Kh [.][128].
// theta = pos*inv1d[j] + c*inv2d[j&15]; Q additionally scaled by 0.125.
// ---------------------------------------------------------------------------
__global__ void rope_f16(_Float16* __restrict__ Qh, _Float16* __restrict__ Kh)
{
    const int NQP = S * HQ * 32;
    const int NKP = NTOK * HKV * 32;
    const int idx = blockIdx.x * 256 + threadIdx.x;
    if (idx >= NQP + NKP) return;

    float pos, cy, cx, scale;
    _Float16* p;
    int j;
    if (idx < NQP) {
        const int s   = idx >> 8;
        const int rem = idx & 255;
        const int h   = rem >> 5;
        j = rem & 31;
        pos = (float)T;
        cy = (float)(s / GRIDN); cx = (float)(s % GRIDN);
        p = Qh + (size_t)s * 512 + h * 64 + 2 * j;
        scale = 0.125f;
    } else {
        const int k   = idx - NQP;
        const int l   = k >> 6;
        const int rem = k & 63;
        const int kvh = rem >> 5;
        j = rem & 31;
        int cell;
        if (l == 0)        { pos = 0.f; cell = 0; }
        else if (l <= T*S) { const int j2 = l - 1; pos = (float)(j2 / S); cell = j2 % S; }
        else               { pos = (float)T; cell = l - CUR0; }
        cy = (float)(cell / GRIDN); cx = (float)(cell % GRIDN);
        p = Kh + (size_t)l * 128 + kvh * 64 + 2 * j;
        scale = 1.f;
    }
    const float LN1E4 = 9.210340371976184f;
    const float inv1 = __expf(-(float)j        * (LN1E4 / 32.f));
    const float inv2 = __expf(-(float)(j & 15) * (LN1E4 / 16.f));
    const float c2 = (j < 16) ? cy : cx;
    const float theta = pos * inv1 + c2 * inv2;
    float sn, cs;
    __sincosf(theta, &sn, &cs);
    const float xr = (float)p[0], xi = (float)p[1];
    p[0] = (_Float16)((xr * cs - xi * sn) * scale);
    p[1] = (_Float16)((xr * sn + xi * cs) * scale);
}

// ---------------------------------------------------------------------------
// V transpose for PV MFMA: Vf fp32 rows [CUR0, CUR0+960) -> Vt fp16 [2][64][VTC].
// ---------------------------------------------------------------------------
__global__ __launch_bounds__(256) void transpose_v(
    const float* __restrict__ Vf, _Float16* __restrict__ Vt)
{
    __shared__ _Float16 tile[64][72];
    const int c0  = blockIdx.x * 64;      // key column base 0..896
    const int kvh = blockIdx.y;
    const int tid = threadIdx.x;
    {
        const int lr = tid >> 2, dq = (tid & 3) * 16;
        const float* src = Vf + (size_t)(CUR0 + c0 + lr) * 128 + kvh * 64 + dq;
        #pragma unroll
        for (int q = 0; q < 4; ++q) {
            const float4 f = *(const float4*)(src + q * 4);
            tile[lr][dq+q*4+0] = (_Float16)f.x;
            tile[lr][dq+q*4+1] = (_Float16)f.y;
            tile[lr][dq+q*4+2] = (_Float16)f.z;
            tile[lr][dq+q*4+3] = (_Float16)f.w;
        }
    }
    __syncthreads();
    {
        const int d = tid >> 2, lg = (tid & 3) * 16;
        _Float16 tmp[16];
        #pragma unroll
        for (int q = 0; q < 16; ++q) tmp[q] = tile[lg + q][d];
        _Float16* dst = Vt + ((size_t)kvh * 64 + d) * VTC + c0 + lg;
        *(half8*)dst       = *(half8*)tmp;
        *(half8*)(dst + 8) = *(half8*)(tmp + 8);
    }
}

// ---------------------------------------------------------------------------
// Attention: block = (16-query tile, head); 4 waves. Dense 900 keys via MFMA
// (scores in registers, softmax via shfl + small LDS), 17 masked keys via VALU.
// ---------------------------------------------------------------------------
__global__ __launch_bounds__(256) void attn_f16(
    const _Float16* __restrict__ Qh, const _Float16* __restrict__ Kh,
    const _Float16* __restrict__ Vt, const float* __restrict__ Vf,
    _Float16* __restrict__ Oh)
{
    __shared__ _Float16 pb[16][PBS];      // exp'd P, fp16, cols 0..927
    __shared__ float ex[16][20];          // extras: raw then exp'd
    __shared__ float wpm[4][16], wps[4][16];
    __shared__ float rowm[16], rowinv[16];
    __shared__ float Oe[16][68];          // extras PV partial

    const int q0  = blockIdx.x * 16;
    const int h   = blockIdx.y;
    const int kvh = h >> 2;
    const int tid = threadIdx.x;
    const int w = tid >> 6, lane = tid & 63;
    const int r = lane & 15, g = lane >> 4;

    // ---- phase A: extras raw scores (thread = (row, e)) ----
    {
        const int er = tid & 15;
        const int s  = q0 + er;
        const int ss = (s < S) ? s : 0;
        const _Float16* qp = Qh + (size_t)(q0 + er) * 512 + h * 64;
        for (int e = tid >> 4; e < 17; e += 16) {
            const int l = (e == 0) ? 0 : (1 + (e - 1) * S + ss);
            const _Float16* kp = Kh + (size_t)l * 128 + kvh * 64;
            float acc = 0.f;
            #pragma unroll
            for (int d8 = 0; d8 < 8; ++d8) {
                const half8 qv = *(const half8*)(qp + d8 * 8);
                const half8 kv = *(const half8*)(kp + d8 * 8);
                #pragma unroll
                for (int jj = 0; jj < 8; ++jj)
                    acc += (float)qv[jj] * (float)kv[jj];
            }
            ex[er][e] = acc;
        }
    }

    // ---- phase B: dense QK^T in registers (wave w owns tiles w,w+4,...) ----
    half8 qa[2];
    #pragma unroll
    for (int ks = 0; ks < 2; ++ks)
        qa[ks] = *(const half8*)(Qh + (size_t)(q0 + r) * 512 + h * 64 + ks * 32 + g * 8);

    floatx4 qacc[15];
    #pragma unroll
    for (int t = 0; t < 15; ++t) {
        const int nt = w + 4 * t;
        floatx4 a = {0.f, 0.f, 0.f, 0.f};
        if (nt <= 56) {
            const _Float16* kp = Kh + (size_t)(CUR0 + nt * 16 + r) * 128 + kvh * 64 + g * 8;
            a = MFMA16(qa[0], *(const half8*)kp, a);
            a = MFMA16(qa[1], *(const half8*)(kp + 32), a);
        }
        qacc[t] = a;
    }

    // per-wave row max (C layout: row = g*4+i, col = key = nt*16 + r)
    float pm[4] = {-1e30f, -1e30f, -1e30f, -1e30f};
    #pragma unroll
    for (int t = 0; t < 15; ++t) {
        const int nt = w + 4 * t;
        const bool valid = (nt <= 56) && !((nt == 56) && (r >= 4));
        #pragma unroll
        for (int i = 0; i < 4; ++i)
            if (valid) pm[i] = fmaxf(pm[i], qacc[t][i]);
    }
    #pragma unroll
    for (int m = 1; m < 16; m <<= 1)
        #pragma unroll
        for (int i = 0; i < 4; ++i)
            pm[i] = fmaxf(pm[i], __shfl_xor(pm[i], m));
    if (r == 0)
        #pragma unroll
        for (int i = 0; i < 4; ++i) wpm[w][g * 4 + i] = pm[i];
    __syncthreads();

    if (tid < 16) {
        float m = fmaxf(fmaxf(wpm[0][tid], wpm[1][tid]), fmaxf(wpm[2][tid], wpm[3][tid]));
        #pragma unroll
        for (int e = 0; e < 17; ++e) m = fmaxf(m, ex[tid][e]);
        rowm[tid] = m;
    }
    __syncthreads();

    // ---- phase C: exp, pb writes (fp16), row sums ----
    {
        const int er = tid & 15;
        for (int e = tid >> 4; e < 17; e += 16)
            ex[er][e] = __expf(ex[er][e] - rowm[er]);
    }
    pb[tid >> 4][912 + (tid & 15)] = (_Float16)0.f;   // zero pad cols 912..927

    float ps[4] = {0.f, 0.f, 0.f, 0.f};
    #pragma unroll
    for (int t = 0; t < 15; ++t) {
        const int nt = w + 4 * t;
        if (nt <= 56) {
            const int c = nt * 16 + r;
            const bool masked = (nt == 56) && (r >= 4);
            #pragma unroll
            for (int i = 0; i < 4; ++i) {
                const int row = g * 4 + i;
                const float e = masked ? 0.f : __expf(qacc[t][i] - rowm[row]);
                ps[i] += e;
                pb[row][c] = (_Float16)e;
            }
        }
    }
    #pragma unroll
    for (int m = 1; m < 16; m <<= 1)
        #pragma unroll
        for (int i = 0; i < 4; ++i) ps[i] += __shfl_xor(ps[i], m);
    if (r == 0)
        #pragma unroll
        for (int i = 0; i < 4; ++i) wps[w][g * 4 + i] = ps[i];
    __syncthreads();

    if (tid < 16) {
        float s_ = wps[0][tid] + wps[1][tid] + wps[2][tid] + wps[3][tid];
        #pragma unroll
        for (int e = 0; e < 17; ++e) s_ += ex[tid][e];
        rowinv[tid] = 1.f / s_;
    }
    __syncthreads();

    // ---- phase D: extras PV (fp32 VALU) -> Oe ----
    {
        const int er = tid & 15, gg = tid >> 4;
        const int s  = q0 + er;
        const int ss = (s < S) ? s : 0;
        float o0 = 0.f, o1 = 0.f, o2 = 0.f, o3 = 0.f;
        for (int e = 0; e < 17; ++e) {
            const int l = (e == 0) ? 0 : (1 + (e - 1) * S + ss);
            const float p = ex[er][e];
            const float4 v = *(const float4*)(Vf + (size_t)l * 128 + kvh * 64 + gg * 4);
            o0 = fmaf(p, v.x, o0); o1 = fmaf(p, v.y, o1);
            o2 = fmaf(p, v.z, o2); o3 = fmaf(p, v.w, o3);
        }
        *(float4*)&Oe[er][gg * 4] = make_float4(o0, o1, o2, o3);
    }

    // ---- phase E: dense PV via MFMA (wave w owns d-tile w) ----
    const int d0 = w * 16;
    floatx4 oa = {0.f, 0.f, 0.f, 0.f};
    const _Float16* vrow = Vt + ((size_t)kvh * 64 + d0 + r) * VTC + g * 8;
    #pragma unroll
    for (int ks = 0; ks < 29; ++ks) {
        const half8 pf = *(const half8*)(&pb[r][ks * 32 + g * 8]);
        const half8 vf = *(const half8*)(vrow + ks * 32);
        oa = MFMA16(pf, vf, oa);
    }
    __syncthreads();   // Oe ready

    #pragma unroll
    for (int i = 0; i < 4; ++i) {
        const int row = g * 4 + i;
        const int s = q0 + row;
        if (s < S) {
            const float o = (oa[i] + Oe[row][d0 + r]) * rowinv[row];
            Oh[(size_t)s * 512 + h * 64 + d0 + r] = (_Float16)o;
        }
    }
}

// ---------------------------------------------------------------------------
extern "C" void kernel_launch(void* const* d_in, const int* in_sizes, int n_in,
                              void* d_out, int out_size, void* d_ws, size_t ws_size,
                              hipStream_t stream)
{
    (void)in_sizes; (void)n_in; (void)out_size; (void)ws_size;
    const float* static_grid = (const float*)d_in[0];
    const float* history     = (const float*)d_in[1];
    const float* init_embed  = (const float*)d_in[2];
    const float* Wq = (const float*)d_in[3];
    const float* Wk = (const float*)d_in[4];
    const float* Wv = (const float*)d_in[5];
    const float* Wo = (const float*)d_in[6];
    float* out = (float*)d_out;

    char* p = (char*)d_ws;
    _Float16* Wqh  = (_Float16*)p;  p += (size_t)262144 * 2;
    _Float16* Whkv = (_Float16*)p;  p += (size_t)131072 * 2;
    _Float16* Woh  = (_Float16*)p;  p += (size_t)262144 * 2;
    _Float16* Kh   = (_Float16*)p;  p += (size_t)KHROWS * 128 * 2;
    float*    Vf   = (float*)p;     p += (size_t)VFROWS * 128 * 4;
    _Float16* Vt   = (_Float16*)p;  p += (size_t)2 * 64 * VTC * 2;
    _Float16* Qh   = (_Float16*)p;  p += (size_t)928 * 512 * 2;
    _Float16* Oh   = (_Float16*)p;  p += (size_t)928 * 512 * 2;

    convert_w<<<320, 256, 0, stream>>>(Wq, Wk, Wv, Wo, Wqh, Whkv, Woh);
    gemm_kv<<<479, 256, 0, stream>>>(init_embed, history, static_grid, Whkv, Kh, Vf);
    gemm_a32<<<dim3(29, 2), 256, 0, stream>>>(static_grid, Wqh, Qh, S);
    {
        const int total = S * HQ * 32 + NTOK * HKV * 32;
        rope_f16<<<(total + 255) / 256, 256, 0, stream>>>(Qh, Kh);
    }
    transpose_v<<<dim3(15, 2), 256, 0, stream>>>(Vf, Vt);
    attn_f16<<<dim3(57, 8), 256, 0, stream>>>(Qh, Kh, Vt, Vf, Oh);
    gemm_a16<<<dim3(29, 2), 256, 0, stream>>>(Oh, Woh, out, S);
}

// Round 3
// 162.096 us; speedup vs baseline: 2.4402x; 1.1023x over previous
//
#include <hip/hip_runtime.h>
#include <math.h>

// Problem constants
static constexpr int GRIDN = 30;
static constexpr int S    = 900;
static constexpr int D    = 512;
static constexpr int HQ   = 8;
static constexpr int HKV  = 2;
static constexpr int T    = 16;
static constexpr int NTOK = 1 + T*S + S;   // 15301
static constexpr int CUR0 = 1 + T*S;       // 14401

static constexpr int THROWS = 15360;       // Th padded rows
static constexpr int VTC    = 960;         // Vt columns
static constexpr int PBS    = 952;         // P LDS row stride (halves)

typedef _Float16 half8 __attribute__((ext_vector_type(8)));
typedef _Float16 half4 __attribute__((ext_vector_type(4)));
typedef float    floatx4 __attribute__((ext_vector_type(4)));

#define MFMA16(a,b,c) __builtin_amdgcn_mfma_f32_16x16x32_f16((a),(b),(c),0,0,0)

__device__ __forceinline__ half8 to_half8(float4 a, float4 b) {
    half8 h;
    h[0]=(_Float16)a.x; h[1]=(_Float16)a.y; h[2]=(_Float16)a.z; h[3]=(_Float16)a.w;
    h[4]=(_Float16)b.x; h[5]=(_Float16)b.y; h[6]=(_Float16)b.z; h[7]=(_Float16)b.w;
    return h;
}

// ---------------------------------------------------------------------------
// prep: fp32 -> fp16 for weights AND all tokens.
// Th rows: 0 = init, 1..14400 = hist, 14401..15300 = cur.
// ---------------------------------------------------------------------------
__global__ __launch_bounds__(256) void prep(
    const float* __restrict__ Wq, const float* __restrict__ Wk,
    const float* __restrict__ Wv, const float* __restrict__ Wo,
    const float* __restrict__ init_e, const float* __restrict__ hist,
    const float* __restrict__ cur,
    _Float16* __restrict__ Wqh, _Float16* __restrict__ Whkv,
    _Float16* __restrict__ Woh, _Float16* __restrict__ Th)
{
    const size_t i8 = ((size_t)blockIdx.x * 256 + threadIdx.x) * 8;
    const float* src; _Float16* dst; size_t off;
    if (i8 < 262144)      { src = Wq; dst = Wqh;          off = i8; }
    else if (i8 < 327680) { src = Wk; dst = Whkv;         off = i8 - 262144; }
    else if (i8 < 393216) { src = Wv; dst = Whkv + 65536; off = i8 - 327680; }
    else if (i8 < 655360) { src = Wo; dst = Woh;          off = i8 - 393216; }
    else {
        const size_t o = i8 - 655360;
        if (o >= (size_t)NTOK * 512) return;
        dst = Th; off = o;
        if (o < 512)                    src = init_e;
        else if (o < (size_t)CUR0*512)  { src = hist; dst = Th + 512; off = o - 512; }
        else                            { src = cur;  dst = Th + (size_t)CUR0*512; off = o - (size_t)CUR0*512; }
    }
    const float4 f0 = *(const float4*)(src + off);
    const float4 f1 = *(const float4*)(src + off + 4);
    *(half8*)(dst + off) = to_half8(f0, f1);
}

// ---------------------------------------------------------------------------
// proj: fused K/V/Q projection + RoPE + V-transpose.
// Blocks 0..478: KV path (32 token rows x 256 cols; waves 0,1 = K, 2,3 = V).
// Blocks 479..536: Q path (32 cur rows x 256 cols, 2 col halves).
// RoPE applied on fp32 accumulators via lane^1 shfl partner.
// ---------------------------------------------------------------------------
__global__ __launch_bounds__(256) void proj(
    const _Float16* __restrict__ Th, const _Float16* __restrict__ Whkv,
    const _Float16* __restrict__ Wqh,
    _Float16* __restrict__ Kh, _Float16* __restrict__ Vh,
    _Float16* __restrict__ Vt, _Float16* __restrict__ Qh)
{
    const int tid = threadIdx.x;
    const int w = tid >> 6, lane = tid & 63;
    const int r = lane & 15, kb = lane >> 4;
    const int bx = blockIdx.x;
    const bool isQ = (bx >= 479);

    int l0, n0;
    const _Float16* B;
    if (!isQ) { l0 = bx * 32; B = Whkv; n0 = 0; }
    else {
        const int qb = bx - 479;
        l0 = CUR0 + (qb >> 1) * 32;
        B = Wqh; n0 = (qb & 1) * 256;
    }

    const _Float16* ap[2];
    #pragma unroll
    for (int mt = 0; mt < 2; ++mt) {
        int l = l0 + mt*16 + r;
        if (l >= NTOK) l = 0;
        ap[mt] = Th + (size_t)l * 512 + kb*8;
    }
    const _Float16* bp[4];
    #pragma unroll
    for (int nt = 0; nt < 4; ++nt)
        bp[nt] = B + (size_t)(n0 + w*64 + nt*16 + r) * 512 + kb*8;

    floatx4 acc[2][4] = {};
    #pragma unroll 2
    for (int k0 = 0; k0 < 512; k0 += 32) {
        half8 a[2], b[4];
        #pragma unroll
        for (int mt = 0; mt < 2; ++mt) a[mt] = *(const half8*)(ap[mt] + k0);
        #pragma unroll
        for (int nt = 0; nt < 4; ++nt) b[nt] = *(const half8*)(bp[nt] + k0);
        #pragma unroll
        for (int mt = 0; mt < 2; ++mt)
            #pragma unroll
            for (int nt = 0; nt < 4; ++nt)
                acc[mt][nt] = MFMA16(a[mt], b[nt], acc[mt][nt]);
    }

    const float LN1E4 = 9.210340371976184f;
    // per-nt rope frequencies (cl = nt*16 + r within a 64-dim head)
    float inv1[4], inv2[4]; int jj[4];
    #pragma unroll
    for (int nt = 0; nt < 4; ++nt) {
        const int cl = nt*16 + r;
        jj[nt] = cl >> 1;
        inv1[nt] = __expf(-(float)jj[nt]        * (LN1E4 / 32.f));
        inv2[nt] = __expf(-(float)(jj[nt] & 15) * (LN1E4 / 16.f));
    }

    if (!isQ) {
        if (w < 2) {
            // ---- K with rope: col = w*64 + cl, kvh = w ----
            #pragma unroll
            for (int mt = 0; mt < 2; ++mt)
                #pragma unroll
                for (int i = 0; i < 4; ++i) {
                    const int l = l0 + mt*16 + kb*4 + i;
                    float pos, cy, cx;
                    if (l == 0) { pos = 0.f; cy = 0.f; cx = 0.f; }
                    else if (l <= T*S) {
                        const int j2 = l - 1;
                        const int t_ = j2 / S;
                        const int cell = j2 - t_ * S;
                        pos = (float)t_;
                        cy = (float)(cell / GRIDN); cx = (float)(cell % GRIDN);
                    } else {
                        const int cell = l - CUR0;
                        pos = (float)T;
                        cy = (float)(cell / GRIDN); cx = (float)(cell % GRIDN);
                    }
                    #pragma unroll
                    for (int nt = 0; nt < 4; ++nt) {
                        const float own = acc[mt][nt][i];
                        const float oth = __shfl_xor(own, 1);
                        const float c2 = (jj[nt] < 16) ? cy : cx;
                        const float theta = pos * inv1[nt] + c2 * inv2[nt];
                        float sn, cs; __sincosf(theta, &sn, &cs);
                        const int cl = nt*16 + r;
                        const float o = ((cl & 1) == 0) ? (own * cs - oth * sn)
                                                        : (oth * sn + own * cs);
                        if (l < NTOK) Kh[(size_t)l * 128 + w*64 + cl] = (_Float16)o;
                    }
                }
        } else {
            // ---- V (no rope): kvh = w-2, d = nt*16 + r ----
            #pragma unroll
            for (int mt = 0; mt < 2; ++mt)
                #pragma unroll
                for (int nt = 0; nt < 4; ++nt) {
                    const int d = nt*16 + r;
                    #pragma unroll
                    for (int i = 0; i < 4; ++i) {
                        const int l = l0 + mt*16 + kb*4 + i;
                        if (l >= NTOK) continue;
                        const _Float16 hv = (_Float16)acc[mt][nt][i];
                        Vh[(size_t)l * 128 + (w-2)*64 + d] = hv;
                        const int cc = l - CUR0;
                        if (cc >= 0 && cc < S)
                            Vt[((size_t)(w-2)*64 + d) * VTC + cc] = hv;
                    }
                }
        }
    } else {
        // ---- Q with rope + 0.125 scale: col = n0 + w*64 + cl ----
        #pragma unroll
        for (int mt = 0; mt < 2; ++mt)
            #pragma unroll
            for (int i = 0; i < 4; ++i) {
                const int l = l0 + mt*16 + kb*4 + i;
                const int s = l - CUR0;
                const float cy = (float)(s / GRIDN), cx = (float)(s % GRIDN);
                #pragma unroll
                for (int nt = 0; nt < 4; ++nt) {
                    const float own = acc[mt][nt][i];
                    const float oth = __shfl_xor(own, 1);
                    const float c2 = (jj[nt] < 16) ? cy : cx;
                    const float theta = 16.f * inv1[nt] + c2 * inv2[nt];
                    float sn, cs; __sincosf(theta, &sn, &cs);
                    const int cl = nt*16 + r;
                    const float o = ((cl & 1) == 0) ? (own * cs - oth * sn)
                                                    : (oth * sn + own * cs);
                    if (s < S)
                        Qh[(size_t)s * 512 + n0 + w*64 + cl] = (_Float16)(o * 0.125f);
                }
            }
    }
}

// ---------------------------------------------------------------------------
// Attention: block = (16-query tile, head); 4 waves. Dense 900 keys via MFMA,
// 17 masked extras (init + same-cell history) via VALU on fp16 V.
// ---------------------------------------------------------------------------
__global__ __launch_bounds__(256) void attn_f16(
    const _Float16* __restrict__ Qh, const _Float16* __restrict__ Kh,
    const _Float16* __restrict__ Vt, const _Float16* __restrict__ Vh,
    _Float16* __restrict__ Oh)
{
    __shared__ _Float16 pb[16][PBS];
    __shared__ float ex[16][20];
    __shared__ float wpm[4][16], wps[4][16];
    __shared__ float rowm[16], rowinv[16];
    __shared__ float Oe[16][68];

    const int q0  = blockIdx.x * 16;
    const int h   = blockIdx.y;
    const int kvh = h >> 2;
    const int tid = threadIdx.x;
    const int w = tid >> 6, lane = tid & 63;
    const int r = lane & 15, g = lane >> 4;

    // ---- phase A: extras raw scores ----
    {
        const int er = tid & 15;
        const int s  = q0 + er;
        const int ss = (s < S) ? s : 0;
        const _Float16* qp = Qh + (size_t)(q0 + er) * 512 + h * 64;
        for (int e = tid >> 4; e < 17; e += 16) {
            const int l = (e == 0) ? 0 : (1 + (e - 1) * S + ss);
            const _Float16* kp = Kh + (size_t)l * 128 + kvh * 64;
            float acc = 0.f;
            #pragma unroll
            for (int d8 = 0; d8 < 8; ++d8) {
                const half8 qv = *(const half8*)(qp + d8 * 8);
                const half8 kv = *(const half8*)(kp + d8 * 8);
                #pragma unroll
                for (int q_ = 0; q_ < 8; ++q_)
                    acc += (float)qv[q_] * (float)kv[q_];
            }
            ex[er][e] = acc;
        }
    }

    // ---- phase B: dense QK^T in registers ----
    half8 qa[2];
    #pragma unroll
    for (int ks = 0; ks < 2; ++ks)
        qa[ks] = *(const half8*)(Qh + (size_t)(q0 + r) * 512 + h * 64 + ks * 32 + g * 8);

    floatx4 qacc[15];
    #pragma unroll
    for (int t = 0; t < 15; ++t) {
        const int nt = w + 4 * t;
        floatx4 a = {0.f, 0.f, 0.f, 0.f};
        if (nt <= 56) {
            const _Float16* kp = Kh + (size_t)(CUR0 + nt * 16 + r) * 128 + kvh * 64 + g * 8;
            a = MFMA16(qa[0], *(const half8*)kp, a);
            a = MFMA16(qa[1], *(const half8*)(kp + 32), a);
        }
        qacc[t] = a;
    }

    float pm[4] = {-1e30f, -1e30f, -1e30f, -1e30f};
    #pragma unroll
    for (int t = 0; t < 15; ++t) {
        const int nt = w + 4 * t;
        const bool valid = (nt <= 56) && !((nt == 56) && (r >= 4));
        #pragma unroll
        for (int i = 0; i < 4; ++i)
            if (valid) pm[i] = fmaxf(pm[i], qacc[t][i]);
    }
    #pragma unroll
    for (int m = 1; m < 16; m <<= 1)
        #pragma unroll
        for (int i = 0; i < 4; ++i)
            pm[i] = fmaxf(pm[i], __shfl_xor(pm[i], m));
    if (r == 0)
        #pragma unroll
        for (int i = 0; i < 4; ++i) wpm[w][g * 4 + i] = pm[i];
    __syncthreads();

    if (tid < 16) {
        float m = fmaxf(fmaxf(wpm[0][tid], wpm[1][tid]), fmaxf(wpm[2][tid], wpm[3][tid]));
        #pragma unroll
        for (int e = 0; e < 17; ++e) m = fmaxf(m, ex[tid][e]);
        rowm[tid] = m;
    }
    __syncthreads();

    // ---- phase C: exp + row sums ----
    {
        const int er = tid & 15;
        for (int e = tid >> 4; e < 17; e += 16)
            ex[er][e] = __expf(ex[er][e] - rowm[er]);
    }
    pb[tid >> 4][912 + (tid & 15)] = (_Float16)0.f;

    float ps[4] = {0.f, 0.f, 0.f, 0.f};
    #pragma unroll
    for (int t = 0; t < 15; ++t) {
        const int nt = w + 4 * t;
        if (nt <= 56) {
            const int c = nt * 16 + r;
            const bool masked = (nt == 56) && (r >= 4);
            #pragma unroll
            for (int i = 0; i < 4; ++i) {
                const int row = g * 4 + i;
                const float e = masked ? 0.f : __expf(qacc[t][i] - rowm[row]);
                ps[i] += e;
                pb[row][c] = (_Float16)e;
            }
        }
    }
    #pragma unroll
    for (int m = 1; m < 16; m <<= 1)
        #pragma unroll
        for (int i = 0; i < 4; ++i) ps[i] += __shfl_xor(ps[i], m);
    if (r == 0)
        #pragma unroll
        for (int i = 0; i < 4; ++i) wps[w][g * 4 + i] = ps[i];
    __syncthreads();

    if (tid < 16) {
        float s_ = wps[0][tid] + wps[1][tid] + wps[2][tid] + wps[3][tid];
        #pragma unroll
        for (int e = 0; e < 17; ++e) s_ += ex[tid][e];
        rowinv[tid] = 1.f / s_;
    }
    __syncthreads();

    // ---- phase D: extras PV (fp16 V, fp32 accum) ----
    {
        const int er = tid & 15, gg = tid >> 4;
        const int s  = q0 + er;
        const int ss = (s < S) ? s : 0;
        float o0 = 0.f, o1 = 0.f, o2 = 0.f, o3 = 0.f;
        for (int e = 0; e < 17; ++e) {
            const int l = (e == 0) ? 0 : (1 + (e - 1) * S + ss);
            const float p = ex[er][e];
            const half4 v = *(const half4*)(Vh + (size_t)l * 128 + kvh * 64 + gg * 4);
            o0 = fmaf(p, (float)v[0], o0); o1 = fmaf(p, (float)v[1], o1);
            o2 = fmaf(p, (float)v[2], o2); o3 = fmaf(p, (float)v[3], o3);
        }
        *(float4*)&Oe[er][gg * 4] = make_float4(o0, o1, o2, o3);
    }

    // ---- phase E: dense PV via MFMA ----
    const int d0 = w * 16;
    floatx4 oa = {0.f, 0.f, 0.f, 0.f};
    const _Float16* vrow = Vt + ((size_t)kvh * 64 + d0 + r) * VTC + g * 8;
    #pragma unroll
    for (int ks = 0; ks < 29; ++ks) {
        const half8 pf = *(const half8*)(&pb[r][ks * 32 + g * 8]);
        const half8 vf = *(const half8*)(vrow + ks * 32);
        oa = MFMA16(pf, vf, oa);
    }
    __syncthreads();

    #pragma unroll
    for (int i = 0; i < 4; ++i) {
        const int row = g * 4 + i;
        const int s = q0 + row;
        if (s < S) {
            const float o = (oa[i] + Oe[row][d0 + r]) * rowinv[row];
            Oh[(size_t)s * 512 + h * 64 + d0 + r] = (_Float16)o;
        }
    }
}

// ---------------------------------------------------------------------------
// Out(fp32)[M][512] = A(fp16, padded rows)[.][512] @ Wh^T.
// ---------------------------------------------------------------------------
__global__ __launch_bounds__(256) void gemm_out(
    const _Float16* __restrict__ A, const _Float16* __restrict__ Wh,
    float* __restrict__ Out, int M)
{
    const int tid = threadIdx.x;
    const int w = tid >> 6, lane = tid & 63;
    const int r = lane & 15, kb = lane >> 4;
    const int l0 = blockIdx.x * 32;
    const int n0 = blockIdx.y * 256 + w*64;

    const _Float16* ap[2];
    #pragma unroll
    for (int mt = 0; mt < 2; ++mt)
        ap[mt] = A + (size_t)(l0 + mt*16 + r)*512 + kb*8;
    const _Float16* bp[4];
    #pragma unroll
    for (int nt = 0; nt < 4; ++nt)
        bp[nt] = Wh + (size_t)(n0 + nt*16 + r) * 512 + kb*8;

    floatx4 acc[2][4] = {};
    #pragma unroll 2
    for (int k0 = 0; k0 < 512; k0 += 32) {
        half8 a[2], b[4];
        #pragma unroll
        for (int mt = 0; mt < 2; ++mt) a[mt] = *(const half8*)(ap[mt] + k0);
        #pragma unroll
        for (int nt = 0; nt < 4; ++nt) b[nt] = *(const half8*)(bp[nt] + k0);
        #pragma unroll
        for (int mt = 0; mt < 2; ++mt)
            #pragma unroll
            for (int nt = 0; nt < 4; ++nt)
                acc[mt][nt] = MFMA16(a[mt], b[nt], acc[mt][nt]);
    }
    #pragma unroll
    for (int mt = 0; mt < 2; ++mt)
        #pragma unroll
        for (int nt = 0; nt < 4; ++nt)
            #pragma unroll
            for (int i = 0; i < 4; ++i) {
                const int l = l0 + mt*16 + kb*4 + i;
                if (l < M)
                    Out[(size_t)l*512 + n0 + nt*16 + r] = acc[mt][nt][i];
            }
}

// ---------------------------------------------------------------------------
extern "C" void kernel_launch(void* const* d_in, const int* in_sizes, int n_in,
                              void* d_out, int out_size, void* d_ws, size_t ws_size,
                              hipStream_t stream)
{
    (void)in_sizes; (void)n_in; (void)out_size; (void)ws_size;
    const float* static_grid = (const float*)d_in[0];
    const float* history     = (const float*)d_in[1];
    const float* init_embed  = (const float*)d_in[2];
    const float* Wq = (const float*)d_in[3];
    const float* Wk = (const float*)d_in[4];
    const float* Wv = (const float*)d_in[5];
    const float* Wo = (const float*)d_in[6];
    float* out = (float*)d_out;

    char* p = (char*)d_ws;
    _Float16* Wqh  = (_Float16*)p;  p += (size_t)262144 * 2;
    _Float16* Whkv = (_Float16*)p;  p += (size_t)131072 * 2;
    _Float16* Woh  = (_Float16*)p;  p += (size_t)262144 * 2;
    _Float16* Th   = (_Float16*)p;  p += (size_t)THROWS * 512 * 2;
    _Float16* Kh   = (_Float16*)p;  p += (size_t)THROWS * 128 * 2;
    _Float16* Vh   = (_Float16*)p;  p += (size_t)THROWS * 128 * 2;
    _Float16* Vt   = (_Float16*)p;  p += (size_t)2 * 64 * VTC * 2;
    _Float16* Qh   = (_Float16*)p;  p += (size_t)928 * 512 * 2;
    _Float16* Oh   = (_Float16*)p;  p += (size_t)928 * 512 * 2;

    // 1) convert weights + tokens to fp16
    prep<<<4146, 256, 0, stream>>>(Wq, Wk, Wv, Wo, init_embed, history,
                                   static_grid, Wqh, Whkv, Woh, Th);
    // 2) fused K/V/Q projection + RoPE + V transpose
    proj<<<537, 256, 0, stream>>>(Th, Whkv, Wqh, Kh, Vh, Vt, Qh);
    // 3) masked attention
    attn_f16<<<dim3(57, 8), 256, 0, stream>>>(Qh, Kh, Vt, Vh, Oh);
    // 4) output projection
    gemm_out<<<dim3(29, 2), 256, 0, stream>>>(Oh, Woh, out, S);
}